// Round 1
// baseline (328.946 us; speedup 1.0000x reference)
//
#include <hip/hip_runtime.h>
#include <hip/hip_bf16.h>
#include <stdint.h>

// B=2, SQ=2048, SE=2048, SKV=4096, H=1024, NH=16, HD=64
// fp32 in/out; internal compute bf16 MFMA (threshold 4.94e-3 allows it).

typedef __attribute__((ext_vector_type(8))) short short8;
typedef __attribute__((ext_vector_type(4))) float f32x4;
typedef __attribute__((ext_vector_type(4))) unsigned short us4;

#define DEV static __device__ __forceinline__

DEV unsigned short f2bf(float f) {
  unsigned int u = __builtin_bit_cast(unsigned int, f);
  u += 0x7fffu + ((u >> 16) & 1u);   // RNE
  return (unsigned short)(u >> 16);
}

DEV void g2lds16(const void* g, void* l) {
  // async global->LDS, 16B per lane; LDS dest = wave-uniform base + lane*16
  __builtin_amdgcn_global_load_lds((const __attribute__((address_space(1))) void*)g,
                                   (__attribute__((address_space(3))) void*)l, 16, 0, 0);
}

// ---------- input conversion: all_hs = concat(hidden, encoder) -> bf16 ----------
__global__ __launch_bounds__(256) void convert_allhs(const float* __restrict__ hid,
                                                     const float* __restrict__ enc,
                                                     unsigned short* __restrict__ ah) {
  int idx = blockIdx.x * 256 + threadIdx.x;      // one float4 group each; 2,097,152 total
  const int perB = 4096 * 256;                   // f4 groups per batch
  int b = idx / perB, r = idx - b * perB;
  int s = r >> 8, c4 = r & 255;
  const float* srcrow = (s < 2048) ? hid + (size_t)(b * 2048 + s) * 1024
                                   : enc + (size_t)(b * 2048 + (s - 2048)) * 1024;
  f32x4 v = *(const f32x4*)(srcrow + c4 * 4);
  us4 o;
  o[0] = f2bf(v[0]); o[1] = f2bf(v[1]); o[2] = f2bf(v[2]); o[3] = f2bf(v[3]);
  *(us4*)(ah + (size_t)idx * 4) = o;
}

// ---------- weight transpose: Wt[n][k] = bf16(W[k][n]) ----------
__global__ __launch_bounds__(256) void transpose_w(const float* __restrict__ W,
                                                   unsigned short* __restrict__ Wt) {
  __shared__ unsigned short t[64][65];
  int k0 = blockIdx.y * 64, n0 = blockIdx.x * 64;
  int tid = threadIdx.x;
#pragma unroll
  for (int rep = 0; rep < 16; rep++) {
    int idx = rep * 256 + tid;
    int kk = idx >> 6, nn = idx & 63;
    t[kk][nn] = f2bf(W[(size_t)(k0 + kk) * 1024 + n0 + nn]);
  }
  __syncthreads();
#pragma unroll
  for (int rep = 0; rep < 16; rep++) {
    int idx = rep * 256 + tid;
    int nn = idx >> 6, kk = idx & 63;
    Wt[(size_t)(n0 + nn) * 1024 + k0 + kk] = t[kk][nn];
  }
}

// ---------- NT GEMM: D[r][c] = sum_k R1[r][k]*R2[c][k] (both row-major in k, K=1024) ----------
// MODE 0 (Q/K): R1=Wt (r=n=h*64+d), R2=tokens (c=s). out[((r>>6)*S + c)*64 + (r&63)] + bias[r]
// MODE 1 (V):   R1=tokens (r=s),    R2=Wt     (c=n). out[c*S + r] + bias[c]   (transposed V)
template <int MODE>
__global__ __launch_bounds__(256) void gemm_nt(const unsigned short* __restrict__ R1, long r1bs,
                                               const unsigned short* __restrict__ R2, long r2bs,
                                               const float* __restrict__ bias,
                                               unsigned short* __restrict__ outp, long obs, int S) {
  __shared__ unsigned short ldsA[128 * 32];
  __shared__ unsigned short ldsB[128 * 32];
  const int b = blockIdx.z;
  const unsigned short* A = R1 + (size_t)b * r1bs;
  const unsigned short* Bm = R2 + (size_t)b * r2bs;
  unsigned short* outb = outp + (size_t)b * obs;
  const int r0 = blockIdx.y * 128, c0 = blockIdx.x * 128;
  const int tid = threadIdx.x, w = tid >> 6, l = tid & 63;
  const int wr = w >> 1, wc = w & 1;
  const int lrow = l >> 2, lk = (l & 3) * 8;
  const int lc = l & 15, g = l >> 4;

  f32x4 acc[4][4];
#pragma unroll
  for (int i = 0; i < 4; i++)
#pragma unroll
    for (int j = 0; j < 4; j++) acc[i][j] = (f32x4){0.f, 0.f, 0.f, 0.f};

  for (int k0 = 0; k0 < 1024; k0 += 32) {
#pragma unroll
    for (int t = 0; t < 2; t++) {
      const int tt = w * 2 + t;  // 16 rows per wave-load, 8 loads cover 128 rows
      g2lds16(A + (size_t)(r0 + tt * 16 + lrow) * 1024 + k0 + lk, (char*)ldsA + tt * 1024);
      g2lds16(Bm + (size_t)(c0 + tt * 16 + lrow) * 1024 + k0 + lk, (char*)ldsB + tt * 1024);
    }
    __syncthreads();
    short8 af[4], bf[4];
#pragma unroll
    for (int f = 0; f < 4; f++) {
      af[f] = *(const short8*)((const char*)ldsA + (wr * 64 + f * 16 + lc) * 64 + g * 16);
      bf[f] = *(const short8*)((const char*)ldsB + (wc * 64 + f * 16 + lc) * 64 + g * 16);
    }
#pragma unroll
    for (int fr = 0; fr < 4; fr++)
#pragma unroll
      for (int fc = 0; fc < 4; fc++)
        acc[fr][fc] = __builtin_amdgcn_mfma_f32_16x16x32_bf16(af[fr], bf[fc], acc[fr][fc], 0, 0, 0);
    __syncthreads();
  }

#pragma unroll
  for (int fr = 0; fr < 4; fr++) {
    int rb = r0 + wr * 64 + fr * 16 + g * 4;
    float bv[4];
    if (MODE == 0) {
#pragma unroll
      for (int i = 0; i < 4; i++) bv[i] = bias[rb + i];
    }
#pragma unroll
    for (int fc = 0; fc < 4; fc++) {
      int c = c0 + wc * 64 + fc * 16 + lc;
      float bc = (MODE == 0) ? 0.f : bias[c];
      us4 pk;
#pragma unroll
      for (int i = 0; i < 4; i++) {
        float v = acc[fr][fc][i] + (MODE == 0 ? bv[i] : bc);
        pk[i] = f2bf(v);
      }
      size_t addr;
      if (MODE == 0) addr = ((size_t)(rb >> 6) * S + c) * 64 + (rb & 63);
      else           addr = (size_t)c * S + rb;
      *(us4*)(outb + addr) = pk;
    }
  }
}

// ---------- flash attention (swapped operands) ----------
// Q[b][h][sq][d], K[b][h][skv][d], Vt[b][h][d][skv]  (bf16); out fp32 [B][SQ][H]
// block: 4 waves x 32 sq rows = 128 sq. Per wave: S^T = mfma(K, Q), ctx^T = mfma(V^T, P^T).
__global__ __launch_bounds__(256) void attn_kernel(const unsigned short* __restrict__ Q,
                                                   const unsigned short* __restrict__ K,
                                                   const unsigned short* __restrict__ Vt,
                                                   const float* __restrict__ mask,
                                                   float* __restrict__ out) {
  __shared__ float mlds[4096];
  __shared__ unsigned short plds[8192];  // [4 waves][2 c2][16 sq][64 skv] bf16, XOR-swizzled
  const int qt = blockIdx.x, h = blockIdx.y, b = blockIdx.z;
  const int tid = threadIdx.x, w = tid >> 6, l = tid & 63;
  const int lc = l & 15, g = l >> 4;

  const float* mb = mask + (size_t)b * 4096;
#pragma unroll
  for (int i = 0; i < 4; i++) {
    int f4 = i * 256 + tid;
    *(f32x4*)(mlds + f4 * 4) = *(const f32x4*)(mb + f4 * 4);
  }
  __syncthreads();

  const unsigned short* Qb = Q + ((size_t)(b * 16 + h) * 2048) * 64;
  const unsigned short* Kb = K + ((size_t)(b * 16 + h) * 4096) * 64;
  const unsigned short* Vb = Vt + ((size_t)(b * 16 + h) * 64) * 4096;
  const int sq0 = qt * 128 + w * 32;

  short8 qf[2][2];
#pragma unroll
  for (int c2 = 0; c2 < 2; c2++)
#pragma unroll
    for (int hh = 0; hh < 2; hh++)
      qf[c2][hh] = *(const short8*)(Qb + (size_t)(sq0 + c2 * 16 + lc) * 64 + hh * 32 + g * 8);

  f32x4 ctx[2][4];
#pragma unroll
  for (int c2 = 0; c2 < 2; c2++)
#pragma unroll
    for (int df = 0; df < 4; df++) ctx[c2][df] = (f32x4){0.f, 0.f, 0.f, 0.f};
  float m[2] = {-1e30f, -1e30f}, ls[2] = {0.f, 0.f};
  const float SCALE = 0.125f;
  char* pwave = (char*)plds + w * 4096;
  const int swz = (lc & 7) << 4;

  for (int s0 = 0; s0 < 4096; s0 += 64) {
    short8 kf[4][2];
#pragma unroll
    for (int f = 0; f < 4; f++)
#pragma unroll
      for (int hh = 0; hh < 2; hh++)
        kf[f][hh] = *(const short8*)(Kb + (size_t)(s0 + f * 16 + lc) * 64 + hh * 32 + g * 8);
    float mv[4][4];
#pragma unroll
    for (int f = 0; f < 4; f++)
#pragma unroll
      for (int i = 0; i < 4; i++) mv[f][i] = mlds[s0 + f * 16 + g * 4 + i];

#pragma unroll
    for (int c2 = 0; c2 < 2; c2++) {
      f32x4 st[4];
#pragma unroll
      for (int f = 0; f < 4; f++) {
        f32x4 z = (f32x4){0.f, 0.f, 0.f, 0.f};
        z = __builtin_amdgcn_mfma_f32_16x16x32_bf16(kf[f][0], qf[c2][0], z, 0, 0, 0);
        z = __builtin_amdgcn_mfma_f32_16x16x32_bf16(kf[f][1], qf[c2][1], z, 0, 0, 0);
        st[f] = z;
      }
      float sc[4][4];
      float tm = -1e30f;
#pragma unroll
      for (int f = 0; f < 4; f++)
#pragma unroll
        for (int i = 0; i < 4; i++) {
          sc[f][i] = st[f][i] * SCALE + mv[f][i];
          tm = fmaxf(tm, sc[f][i]);
        }
      tm = fmaxf(tm, __shfl_xor(tm, 16, 64));
      tm = fmaxf(tm, __shfl_xor(tm, 32, 64));
      float mnew = fmaxf(m[c2], tm);
      float alpha = __expf(m[c2] - mnew);
      float psum = 0.f;
      unsigned int pk[4][2];
#pragma unroll
      for (int f = 0; f < 4; f++) {
        float p0 = __expf(sc[f][0] - mnew);
        float p1 = __expf(sc[f][1] - mnew);
        float p2 = __expf(sc[f][2] - mnew);
        float p3 = __expf(sc[f][3] - mnew);
        psum += (p0 + p1) + (p2 + p3);
        pk[f][0] = (unsigned)f2bf(p0) | ((unsigned)f2bf(p1) << 16);
        pk[f][1] = (unsigned)f2bf(p2) | ((unsigned)f2bf(p3) << 16);
      }
      psum += __shfl_xor(psum, 16, 64);
      psum += __shfl_xor(psum, 32, 64);
      ls[c2] = ls[c2] * alpha + psum;
      m[c2] = mnew;
#pragma unroll
      for (int df = 0; df < 4; df++) ctx[c2][df] *= alpha;
      char* pb = pwave + c2 * 2048;
#pragma unroll
      for (int f = 0; f < 4; f++) {
        int base = lc * 128 + (f * 16 + g * 4) * 2;
        *(unsigned int*)(pb + ((base) ^ swz)) = pk[f][0];
        *(unsigned int*)(pb + ((base + 4) ^ swz)) = pk[f][1];
      }
    }

    // PV: ctx^T += V^T * P^T
    short8 pfrag[2][2];
#pragma unroll
    for (int c2 = 0; c2 < 2; c2++)
#pragma unroll
      for (int kk = 0; kk < 2; kk++)
        pfrag[c2][kk] = *(const short8*)(pwave + c2 * 2048 + ((lc * 128 + kk * 64 + g * 16) ^ swz));
#pragma unroll
    for (int df = 0; df < 4; df++) {
      short8 va[2];
#pragma unroll
      for (int kk = 0; kk < 2; kk++)
        va[kk] = *(const short8*)(Vb + (size_t)(df * 16 + lc) * 4096 + s0 + kk * 32 + g * 8);
#pragma unroll
      for (int c2 = 0; c2 < 2; c2++) {
        ctx[c2][df] = __builtin_amdgcn_mfma_f32_16x16x32_bf16(va[0], pfrag[c2][0], ctx[c2][df], 0, 0, 0);
        ctx[c2][df] = __builtin_amdgcn_mfma_f32_16x16x32_bf16(va[1], pfrag[c2][1], ctx[c2][df], 0, 0, 0);
      }
    }
  }

#pragma unroll
  for (int c2 = 0; c2 < 2; c2++) {
    float inv = 1.f / ls[c2];
    size_t row = (size_t)(b * 2048 + sq0 + c2 * 16 + lc);
#pragma unroll
    for (int df = 0; df < 4; df++) {
      f32x4 o = ctx[c2][df] * inv;
      *(f32x4*)(out + row * 1024 + h * 64 + df * 16 + g * 4) = o;
    }
  }
}

// ---------- launcher ----------
extern "C" void kernel_launch(void* const* d_in, const int* in_sizes, int n_in,
                              void* d_out, int out_size, void* d_ws, size_t ws_size,
                              hipStream_t stream) {
  const float* hid = (const float*)d_in[0];
  const float* enc = (const float*)d_in[1];
  const float* mask = (const float*)d_in[2];
  const float* Wq = (const float*)d_in[3];
  const float* bq = (const float*)d_in[4];
  const float* Wk = (const float*)d_in[5];
  const float* bk = (const float*)d_in[6];
  const float* Wv = (const float*)d_in[7];
  const float* bv = (const float*)d_in[8];

  unsigned short* ws = (unsigned short*)d_ws;
  unsigned short* WTQ = ws;                    // 1M elems
  unsigned short* WTK = ws + 1048576;          // 1M
  unsigned short* WTV = ws + 2097152;          // 1M
  unsigned short* AH  = ws + 3145728;          // 8M  [B][4096][1024]
  unsigned short* Qb  = ws + 11534336;         // 4M  [B][16][2048][64]
  unsigned short* Kb  = ws + 15728640;         // 8M  [B][16][4096][64]
  unsigned short* VT  = ws + 24117248;         // 8M  [B][16][64][4096]
  // total 62 MiB of d_ws

  convert_allhs<<<8192, 256, 0, stream>>>(hid, enc, AH);
  transpose_w<<<dim3(16, 16), 256, 0, stream>>>(Wq, WTQ);
  transpose_w<<<dim3(16, 16), 256, 0, stream>>>(Wk, WTK);
  transpose_w<<<dim3(16, 16), 256, 0, stream>>>(Wv, WTV);

  gemm_nt<0><<<dim3(16, 8, 2), 256, 0, stream>>>(WTQ, 0, AH, 4194304, bq, Qb, 2097152, 2048);
  gemm_nt<0><<<dim3(32, 8, 2), 256, 0, stream>>>(WTK, 0, AH, 4194304, bk, Kb, 4194304, 4096);
  gemm_nt<1><<<dim3(8, 32, 2), 256, 0, stream>>>(AH, 4194304, WTV, 0, bv, VT, 4194304, 4096);

  attn_kernel<<<dim3(16, 16, 2), 256, 0, stream>>>(Qb, Kb, VT, mask, (float*)d_out);
}